// Round 8
// baseline (217.755 us; speedup 1.0000x reference)
//
#include <hip/hip_runtime.h>
#include <hip/hip_bf16.h>
#include <stdint.h>

// ---------------------------------------------------------------------------
// SupervisedContrastiveLoss, B=4096, D=1024, C=32, T=0.1, eps=1e-8
// out = (1/B) * [ sum_i (log(denom_i)*W_i - posS_i) - pw*INV_T*||G||_F^2 ]
// R8: ATOMIC-FREE hot path. Full-matrix row-owned GEMM (2x MFMA, no col
//     reductions): wave owns 64 rows x 256 cols, E/P row-sums accumulate in
//     registers, single plain store per (colg,row) partial. G-units store
//     per-ks partials. finalize reduces partials; only 16 oacc atomics total.
//     (R2..R7 invariant ~50us == atomic serialization: WRITE_SIZE ~ #atomics.)
// ---------------------------------------------------------------------------

typedef float f32x4 __attribute__((ext_vector_type(4)));
typedef float f32x2 __attribute__((ext_vector_type(2)));
typedef long i64;

#define INV_T 10.0f
#define Z_SCALE (INV_T / 256.0f)   // both fp8 operands carry x16

// workspace layout (bytes)
#define OFF_RNF8  0                      // packed fp8 frags: 256 slabs * 16 KB = 4 MB
#define OFF_ZERO  4194304                // 4 KB zeroed region
#define OFF_OACC  OFF_ZERO               // double
#define OFF_DONE  (OFF_ZERO + 16)        // int
#define OFF_CSP   (OFF_ZERO + 4096)      // 32*32*4 colsum partials
#define OFF_CCP   (OFF_CSP + 4096)       // 32*32*4 histogram partials
#define OFF_ERP   (OFF_CCP + 4096)       // ERp[16][4096] f32 = 256 KB (full coverage)
#define OFF_PRP   (OFF_ERP + 262144)     // PRp[16][4096] f32 = 256 KB
#define OFF_GP    (OFF_PRP + 262144)     // Gp[32][1024][32] f32 = 4 MB (full coverage)

// ---------------- D1: normalize+pack (256) | prep (32) | zero (1) -----------
__global__ __launch_bounds__(256) void scl_stage1(const float* __restrict__ rep,
                                                  const float* __restrict__ sl,
                                                  const int* __restrict__ labels,
                                                  uint8_t* __restrict__ rnP,
                                                  float* __restrict__ cs_part,
                                                  int* __restrict__ cc_part,
                                                  char* __restrict__ zbase) {
    int b = blockIdx.x;
    int t = threadIdx.x;
    if (b < 256) {
        // slab b: rows b*16 .. +15 -> packed 16 KB block in MFMA fragment order
        __shared__ uint32_t Ls32[4096];  // 16 KB packed staging
        int rl = t >> 4, i = t & 15;
        int row = b * 16 + rl;
        const float4* src = (const float4*)(rep + (size_t)row * 1024);
        float s = 0.f;
#pragma unroll
        for (int j = 0; j < 16; ++j) {
            float4 v = src[i + j * 16];
            s += v.x * v.x + v.y * v.y + v.z * v.z + v.w * v.w;
        }
#pragma unroll
        for (int m = 1; m < 16; m <<= 1) s += __shfl_xor(s, m, 64);
        float nf = 16.0f / fmaxf(sqrtf(s), 1e-8f);  // x16 into fp8 normal range
        // col c = i*4 + j*64 -> kt=j*2+(i>>3), g2=(i>>1)&3, byte=(i&1)*4, m=rl
        int g2 = (i >> 1) & 3;
        int dw = ((g2 * 16 + rl) * 8 + (i & 1) * 4) >> 2;
#pragma unroll
        for (int j = 0; j < 16; ++j) {
            float4 v = src[i + j * 16];
            int pk = 0;
            pk = __builtin_amdgcn_cvt_pk_fp8_f32(v.x * nf, v.y * nf, pk, false);
            pk = __builtin_amdgcn_cvt_pk_fp8_f32(v.z * nf, v.w * nf, pk, true);
            int kt = j * 2 + (i >> 3);
            Ls32[kt * 128 + dw] = (uint32_t)pk;
        }
        __syncthreads();
        uint4* dst = (uint4*)(rnP + (size_t)b * 16384);
        const uint4* srcl = (const uint4*)Ls32;
#pragma unroll
        for (int q = 0; q < 4; ++q) dst[t * 4 + q] = srcl[t * 4 + q];
    } else if (b < 288) {
        // prep partials: colsum of soft_labels + class histogram (128 rows/slab)
        __shared__ float part[8][32];
        __shared__ int bins[32];
        int bb = b - 256;
        if (t < 32) bins[t] = 0;
        __syncthreads();
        if (t < 128) atomicAdd(&bins[labels[bb * 128 + t]], 1);
        int c = t & 31, rg = t >> 5;
        float s = 0.f;
#pragma unroll 4
        for (int k = 0; k < 16; ++k) {
            int i = bb * 128 + rg * 16 + k;
            s += sl[i * 32 + c];
        }
        part[rg][c] = s;
        __syncthreads();
        if (t < 32) {
            float tot = 0.f;
#pragma unroll
            for (int g = 0; g < 8; ++g) tot += part[g][t];
            cs_part[bb * 32 + t] = tot;
            cc_part[bb * 32 + t] = bins[t];
        }
    } else {
        // zero 4 KB region (oacc, done)
        *(uint4*)(zbase + t * 16) = (uint4){0, 0, 0, 0};
    }
}

// ---------------- D2: atomic-free gemm (1 wave / 64x256 strip) + G units ----
// blocks [0,1024): gemm, bi=blk>>4 (64-row band), colg=blk&15 (256 cols).
// blocks [1024,2048): G units (dblk 0..31, ks 0..31) -> Gp partial store.
__global__ __launch_bounds__(64) void scl_main(const uint8_t* __restrict__ rnP,
                                               const float* __restrict__ sl,
                                               const int* __restrict__ labels,
                                               float* __restrict__ ERp,
                                               float* __restrict__ PRp,
                                               float* __restrict__ Gp) {
    int lane = threadIdx.x;

    if (blockIdx.x >= 1024) {
        // ---- G unit: 32 d x 128 rows -> Gp[ks][d][c], plain stores ----
        int u = blockIdx.x - 1024;
        int dblk = u & 31, ks = u >> 5;
        int c = lane & 31, dq = lane >> 5;  // dq in {0,1}
        f32x2 acc2[8];
#pragma unroll
        for (int j = 0; j < 8; ++j) acc2[j] = (f32x2){0.f, 0.f};
        int i0 = ks * 128;
#pragma unroll 2
        for (int k = 0; k < 128; ++k) {
            int i = i0 + k;
            const uint8_t* fb = rnP + (size_t)(i >> 4) * 16384 + dblk * 512 +
                                (dq * 32 + (i & 15)) * 8;
            uint2 r01 = *(const uint2*)fb;          // d0..d7
            uint2 r23 = *(const uint2*)(fb + 128);  // d8..d15
            float sv = sl[i * 32 + c];
            f32x2 sv2 = {sv, sv};
            acc2[0] += __builtin_amdgcn_cvt_pk_f32_fp8((int)r01.x, false) * sv2;
            acc2[1] += __builtin_amdgcn_cvt_pk_f32_fp8((int)r01.x, true) * sv2;
            acc2[2] += __builtin_amdgcn_cvt_pk_f32_fp8((int)r01.y, false) * sv2;
            acc2[3] += __builtin_amdgcn_cvt_pk_f32_fp8((int)r01.y, true) * sv2;
            acc2[4] += __builtin_amdgcn_cvt_pk_f32_fp8((int)r23.x, false) * sv2;
            acc2[5] += __builtin_amdgcn_cvt_pk_f32_fp8((int)r23.x, true) * sv2;
            acc2[6] += __builtin_amdgcn_cvt_pk_f32_fp8((int)r23.y, false) * sv2;
            acc2[7] += __builtin_amdgcn_cvt_pk_f32_fp8((int)r23.y, true) * sv2;
        }
        int d0 = dblk * 32 + dq * 16;
        float* gp = Gp + ((size_t)ks * 1024 + d0) * 32 + c;
#pragma unroll
        for (int j = 0; j < 8; ++j) {
            gp[(2 * j) * 32] = acc2[j][0] * 0.0625f;      // undo x16
            gp[(2 * j + 1) * 32] = acc2[j][1] * 0.0625f;
        }
        return;
    }

    // ---- gemm strip: 64 rows (band bi) x 256 cols (colg), 4 tiles of 64 ----
    int bi = blockIdx.x >> 4, colg = blockIdx.x & 15;
    int rowA0 = bi * 64;
    int m_ = lane & 15, g = lane >> 4;

    const uint8_t* pa[4];
#pragma unroll
    for (int ti = 0; ti < 4; ++ti)
        pa[ti] = rnP + (size_t)(bi * 4 + ti) * 16384 + lane * 8;

    int lr[4][4];
#pragma unroll
    for (int ti = 0; ti < 4; ++ti)
#pragma unroll
        for (int r = 0; r < 4; ++r)
            lr[ti][r] = labels[rowA0 + ti * 16 + g * 4 + r];

    float rE[4][4], rP[4][4];
#pragma unroll
    for (int ti = 0; ti < 4; ++ti)
#pragma unroll
        for (int r = 0; r < 4; ++r) { rE[ti][r] = 0.f; rP[ti][r] = 0.f; }

#define LOADK(KT, AA, BB)                                                      \
    {                                                                          \
        _Pragma("unroll") for (int ti = 0; ti < 4; ++ti) {                     \
            AA[ti] = *(const i64*)(pa[ti] + (KT) * 512);                       \
            BB[ti] = *(const i64*)(pb[ti] + (KT) * 512);                       \
        }                                                                      \
    }
#define MFMAB(AA, BB)                                                          \
    {                                                                          \
        _Pragma("unroll") for (int ti = 0; ti < 4; ++ti)                       \
            _Pragma("unroll") for (int tj = 0; tj < 4; ++tj)                   \
                acc[ti][tj] = __builtin_amdgcn_mfma_f32_16x16x32_fp8_fp8(      \
                    AA[ti], BB[tj], acc[ti][tj], 0, 0, 0);                     \
    }

    for (int ct = 0; ct < 4; ++ct) {
        int colB0 = colg * 256 + ct * 64;
        const uint8_t* pb[4];
#pragma unroll
        for (int tj = 0; tj < 4; ++tj)
            pb[tj] = rnP + (size_t)((colB0 >> 4) + tj) * 16384 + lane * 8;

        f32x4 acc[4][4];
#pragma unroll
        for (int a = 0; a < 4; ++a)
#pragma unroll
            for (int b = 0; b < 4; ++b) acc[a][b] = (f32x4){0.f, 0.f, 0.f, 0.f};

        i64 a0[4], b0[4], a1[4], b1[4];
        LOADK(0, a0, b0);
        LOADK(1, a1, b1);
#pragma unroll
        for (int kt = 0; kt < 32; kt += 2) {
            MFMAB(a0, b0);
            if (kt + 2 < 32) LOADK(kt + 2, a0, b0);
            MFMAB(a1, b1);
            if (kt + 3 < 32) LOADK(kt + 3, a1, b1);
        }

        // accumulate E/P row-sums (C layout: col=lane&15, row=(lane>>4)*4+reg)
        int lcj[4];
#pragma unroll
        for (int tj = 0; tj < 4; ++tj) lcj[tj] = labels[colB0 + tj * 16 + m_];
#pragma unroll
        for (int ti = 0; ti < 4; ++ti) {
#pragma unroll
            for (int tj = 0; tj < 4; ++tj) {
                int gCol = colB0 + tj * 16 + m_;
                int lc = lcj[tj];
                f32x4 a = acc[ti][tj];
#pragma unroll
                for (int r = 0; r < 4; ++r) {
                    int gRow = rowA0 + ti * 16 + g * 4 + r;
                    float z = Z_SCALE * a[r];
                    float e = __expf(z);
                    bool offd = (gRow != gCol);
                    if (!offd) e = 0.f;
                    rE[ti][r] += e;
                    if (offd && (lr[ti][r] == lc)) rP[ti][r] += z;
                }
            }
        }
    }
#undef LOADK
#undef MFMAB

    // reduce across the 16 col-lanes, single plain store per row partial
#pragma unroll
    for (int ti = 0; ti < 4; ++ti)
#pragma unroll
        for (int r = 0; r < 4; ++r) {
            float v = rE[ti][r], p = rP[ti][r];
#pragma unroll
            for (int msk = 1; msk < 16; msk <<= 1) {
                v += __shfl_xor(v, msk, 64);
                p += __shfl_xor(p, msk, 64);
            }
            if (m_ == 0) {
                int row = rowA0 + ti * 16 + g * 4 + r;
                ERp[colg * 4096 + row] = v;
                PRp[colg * 4096 + row] = p;
            }
        }
}

// ---------------- D3: finalize (8 row-blocks + 8 G-blocks), done-counter ----
__global__ __launch_bounds__(256) void scl_finalize(const float* __restrict__ ERp,
                                                    const float* __restrict__ PRp,
                                                    const float* __restrict__ sl,
                                                    const int* __restrict__ labels,
                                                    const float* __restrict__ cs_part,
                                                    const int* __restrict__ cc_part,
                                                    const float* __restrict__ Gp,
                                                    const int* __restrict__ pwp,
                                                    double* __restrict__ oacc,
                                                    int* __restrict__ done,
                                                    float* __restrict__ out) {
    int t = threadIdx.x;
    int bits = *pwp;
    float pw = (bits >= -(1 << 22) && bits <= (1 << 22)) ? (float)bits
                                                         : __int_as_float(bits);
    __shared__ double wsum[4];
    double contrib = 0.0;

    if (blockIdx.x < 8) {
        __shared__ __align__(16) float css[32];
        __shared__ int ccs[32];
        if (t < 32) {
            float s = 0.f; int n = 0;
#pragma unroll
            for (int b = 0; b < 32; ++b) {
                s += cs_part[b * 32 + t];
                n += cc_part[b * 32 + t];
            }
            css[t] = s; ccs[t] = n;
        }
        __syncthreads();
        const f32x4* sl4 = (const f32x4*)sl;
        const f32x4* cs4 = (const f32x4*)css;
        double td = 0.0;
#pragma unroll
        for (int h = 0; h < 2; ++h) {
            int i = blockIdx.x * 512 + h * 256 + t;
            float de = 0.f, ps = 0.f;
#pragma unroll
            for (int p = 0; p < 16; ++p) {
                de += ERp[p * 4096 + i];
                ps += PRp[p * 4096 + i];
            }
            float dW = 0.f;
#pragma unroll
            for (int q = 0; q < 8; ++q) {
                f32x4 s = sl4[i * 8 + q];
                f32x4 c = cs4[q];
                dW += s[0] * c[0] + s[1] * c[1] + s[2] * c[2] + s[3] * c[3];
            }
            float Wv = (float)(ccs[labels[i]] - 1) + pw * dW;
            td += (double)(__logf(de) * Wv - ps);
        }
#pragma unroll
        for (int m = 1; m < 64; m <<= 1) td += __shfl_xor(td, m, 64);
        if ((t & 63) == 0) wsum[t >> 6] = td;
        __syncthreads();
        contrib = wsum[0] + wsum[1] + wsum[2] + wsum[3];
    } else {
        // G-block gb: reduce Gp over 32 ks for d in [gb*128, +128), accumulate ||G||^2
        int gb = blockIdx.x - 8;
        int c = t & 31, dq = t >> 5;  // 8 d-groups of 16
        float gs = 0.f;
#pragma unroll
        for (int dd = 0; dd < 16; ++dd) {
            int d = gb * 128 + dq * 16 + dd;
            float gv = 0.f;
#pragma unroll
            for (int ks = 0; ks < 32; ++ks) gv += Gp[((size_t)ks * 1024 + d) * 32 + c];
            gs += gv * gv;
        }
        double gd = (double)gs;
#pragma unroll
        for (int m = 1; m < 64; m <<= 1) gd += __shfl_xor(gd, m, 64);
        if ((t & 63) == 0) wsum[t >> 6] = gd;
        __syncthreads();
        contrib = -(double)(pw * INV_T) * (wsum[0] + wsum[1] + wsum[2] + wsum[3]);
    }

    if (t == 0) {
        atomicAdd(oacc, contrib);
        __threadfence();
        int old = atomicAdd(done, 1);
        if (old == 15) {  // last of 16 blocks
            double tot = atomicAdd(oacc, 0.0);  // coherent read
            out[0] = (float)(tot * (1.0 / 4096.0));
        }
    }
}

// ---------------------------------------------------------------------------
extern "C" void kernel_launch(void* const* d_in, const int* in_sizes, int n_in,
                              void* d_out, int out_size, void* d_ws, size_t ws_size,
                              hipStream_t stream) {
    const float* rep = (const float*)d_in[0];
    const float* sl = (const float*)d_in[1];
    const int* labels = (const int*)d_in[2];
    const int* pwp = (const int*)d_in[3];

    char* ws = (char*)d_ws;
    uint8_t* rnP = (uint8_t*)(ws + OFF_RNF8);
    double* oacc = (double*)(ws + OFF_OACC);
    int* done = (int*)(ws + OFF_DONE);
    float* cs_part = (float*)(ws + OFF_CSP);
    int* cc_part = (int*)(ws + OFF_CCP);
    float* ERp = (float*)(ws + OFF_ERP);
    float* PRp = (float*)(ws + OFF_PRP);
    float* Gp = (float*)(ws + OFF_GP);

    scl_stage1<<<289, 256, 0, stream>>>(rep, sl, labels, rnP, cs_part, cc_part,
                                        ws + OFF_ZERO);
    scl_main<<<2048, 64, 0, stream>>>(rnP, sl, labels, ERp, PRp, Gp);
    scl_finalize<<<16, 256, 0, stream>>>(ERp, PRp, sl, labels, cs_part, cc_part,
                                         Gp, pwp, oacc, done, (float*)d_out);
}

// Round 9
// 173.857 us; speedup vs baseline: 1.2525x; 1.2525x over previous
//
#include <hip/hip_runtime.h>
#include <hip/hip_bf16.h>
#include <stdint.h>

// ---------------------------------------------------------------------------
// SupervisedContrastiveLoss, B=4096, D=1024, C=32, T=0.1, eps=1e-8
// out = (1/B) * [ sum_i (log(denom_i)*W_i - posS_i) - pw*INV_T*||G||_F^2 ]
// R9: Infinity-Cache-traffic attack. 256x256 tiles (136 upper-tri blocks):
//     staging drops 266 MB -> 70 MB (invariant ~50us == IC-BW ~5 TB/s).
//     Block=256thr/4 waves; wave owns 128x128 (acc 256 VGPR, launch_bounds
//     (256,1)). Packed-frag rnP makes staging linear GLD16 chunks; 128 MFMA
//     per wave-slab vs 16 ds_read + 8 GLD16. One barrier per K-slab.
//     G = 128 fat units on the leftover CUs. Epilogue atomics (exonerated by R8).
// ---------------------------------------------------------------------------

typedef float f32x4 __attribute__((ext_vector_type(4)));
typedef float f32x2 __attribute__((ext_vector_type(2)));
typedef long i64;

#define INV_T 10.0f
#define Z_SCALE (INV_T / 256.0f)   // both fp8 operands carry x16

#define GLD16(gp, lp)                                                          \
    __builtin_amdgcn_global_load_lds(                                          \
        (const __attribute__((address_space(1))) uint32_t*)(gp),               \
        (__attribute__((address_space(3))) uint32_t*)(lp), 16, 0, 0)

// workspace layout (bytes)
#define OFF_RNF8  0                      // packed fp8 frags: 256 slabs * 16 KB = 4 MB
#define OFF_OACC  4194304                // double (zeroed)
#define OFF_DONE  (OFF_OACC + 16)       // int (zeroed)
#define OFF_DENOM (OFF_OACC + 4096)     // 4096*4 (zeroed)
#define OFF_POSS  (OFF_DENOM + 16384)   // 4096*4 (zeroed)
#define ZERO_BYTES 36864                 // 9 * 4096 covers oacc..posS
#define OFF_CSP   (OFF_POSS + 16384)    // 32*32*4 colsum partials
#define OFF_CCP   (OFF_CSP + 4096)      // 32*32*4 histogram partials
#define OFF_GP    (OFF_CCP + 4096)      // Gp[8][1024][32] f32 = 1 MB (full coverage)

// ---------------- D1: normalize+pack (256) | prep (32) | zero (9) -----------
__global__ __launch_bounds__(256) void scl_stage1(const float* __restrict__ rep,
                                                  const float* __restrict__ sl,
                                                  const int* __restrict__ labels,
                                                  uint8_t* __restrict__ rnP,
                                                  float* __restrict__ cs_part,
                                                  int* __restrict__ cc_part,
                                                  char* __restrict__ zbase) {
    int b = blockIdx.x;
    int t = threadIdx.x;
    if (b < 256) {
        // slab b: rows b*16..+15 -> 16 KB block in MFMA fragment order
        __shared__ uint32_t Ls32[4096];
        int rl = t >> 4, i = t & 15;
        int row = b * 16 + rl;
        const float4* src = (const float4*)(rep + (size_t)row * 1024);
        float s = 0.f;
#pragma unroll
        for (int j = 0; j < 16; ++j) {
            float4 v = src[i + j * 16];
            s += v.x * v.x + v.y * v.y + v.z * v.z + v.w * v.w;
        }
#pragma unroll
        for (int m = 1; m < 16; m <<= 1) s += __shfl_xor(s, m, 64);
        float nf = 16.0f / fmaxf(sqrtf(s), 1e-8f);  // x16 into fp8 normal range
        int g2 = (i >> 1) & 3;
        int dw = ((g2 * 16 + rl) * 8 + (i & 1) * 4) >> 2;
#pragma unroll
        for (int j = 0; j < 16; ++j) {
            float4 v = src[i + j * 16];
            int pk = 0;
            pk = __builtin_amdgcn_cvt_pk_fp8_f32(v.x * nf, v.y * nf, pk, false);
            pk = __builtin_amdgcn_cvt_pk_fp8_f32(v.z * nf, v.w * nf, pk, true);
            int kt = j * 2 + (i >> 3);
            Ls32[kt * 128 + dw] = (uint32_t)pk;
        }
        __syncthreads();
        uint4* dst = (uint4*)(rnP + (size_t)b * 16384);
        const uint4* srcl = (const uint4*)Ls32;
#pragma unroll
        for (int q = 0; q < 4; ++q) dst[t * 4 + q] = srcl[t * 4 + q];
    } else if (b < 288) {
        // prep partials: colsum of soft_labels + class histogram (128 rows/slab)
        __shared__ float part[8][32];
        __shared__ int bins[32];
        int bb = b - 256;
        if (t < 32) bins[t] = 0;
        __syncthreads();
        if (t < 128) atomicAdd(&bins[labels[bb * 128 + t]], 1);
        int c = t & 31, rg = t >> 5;
        float s = 0.f;
#pragma unroll 4
        for (int k = 0; k < 16; ++k) {
            int i = bb * 128 + rg * 16 + k;
            s += sl[i * 32 + c];
        }
        part[rg][c] = s;
        __syncthreads();
        if (t < 32) {
            float tot = 0.f;
#pragma unroll
            for (int g = 0; g < 8; ++g) tot += part[g][t];
            cs_part[bb * 32 + t] = tot;
            cc_part[bb * 32 + t] = bins[t];
        }
    } else {
        int zb = b - 288;
        *(uint4*)(zbase + (size_t)zb * 4096 + t * 16) = (uint4){0, 0, 0, 0};
    }
}

// ---------------- D2: 256x256-tile gemm (136) + G units (128) ---------------
__global__ __launch_bounds__(256, 1) void scl_main(const uint8_t* __restrict__ rnP,
                                                   const float* __restrict__ sl,
                                                   const int* __restrict__ labels,
                                                   float* __restrict__ denom,
                                                   float* __restrict__ posS,
                                                   float* __restrict__ Gp) {
    int tid = threadIdx.x;
    int lane = tid & 63, w = tid >> 6;

    if (blockIdx.x >= 136) {
        // ---- G unit: 64 d x 512 rows -> Gp[ks][d][c], plain stores ----
        int u = blockIdx.x - 136;
        int dblk = u & 15, ks = u >> 4;
        int c = tid & 31, dq = tid >> 5;       // dq 0..7
        int d0 = dblk * 64 + dq * 8;
        int ktc = d0 >> 5, g2 = (d0 >> 3) & 3;
        f32x2 acc2[4];
#pragma unroll
        for (int j = 0; j < 4; ++j) acc2[j] = (f32x2){0.f, 0.f};
        int i0 = ks * 512;
#pragma unroll 4
        for (int k = 0; k < 512; ++k) {
            int i = i0 + k;
            const uint8_t* fb = rnP + (size_t)(i >> 4) * 16384 + ktc * 512 +
                                (g2 * 16 + (i & 15)) * 8;
            uint2 rv = *(const uint2*)fb;
            float sv = sl[i * 32 + c];
            f32x2 sv2 = {sv, sv};
            acc2[0] += __builtin_amdgcn_cvt_pk_f32_fp8((int)rv.x, false) * sv2;
            acc2[1] += __builtin_amdgcn_cvt_pk_f32_fp8((int)rv.x, true) * sv2;
            acc2[2] += __builtin_amdgcn_cvt_pk_f32_fp8((int)rv.y, false) * sv2;
            acc2[3] += __builtin_amdgcn_cvt_pk_f32_fp8((int)rv.y, true) * sv2;
        }
        float* gp = Gp + (size_t)ks * 32768 + d0 * 32 + c;
#pragma unroll
        for (int j = 0; j < 4; ++j) {
            gp[(2 * j) * 32] = acc2[j][0] * 0.0625f;      // undo x16
            gp[(2 * j + 1) * 32] = acc2[j][1] * 0.0625f;
        }
        return;
    }

    // ---- gemm tile: 256x256, 4 waves, wave = 128x128 quadrant ----
    __shared__ __align__(16) uint8_t As[2][16384];
    __shared__ __align__(16) uint8_t Bs[2][16384];

    int L = blockIdx.x;
    int bi = 0, rem = L;
    while (rem >= 16 - bi) { rem -= 16 - bi; ++bi; }
    int bj = bi + rem;
    int rowA0 = bi * 256, colB0 = bj * 256;

    int wr = w >> 1, wc = w & 1;
    int m_ = lane & 15, g = lane >> 4;

    f32x4 acc[8][8];
#pragma unroll
    for (int a = 0; a < 8; ++a)
#pragma unroll
        for (int b = 0; b < 8; ++b) acc[a][b] = (f32x4){0.f, 0.f, 0.f, 0.f};

    // linear staging: 1-KB packed chunk == one wave-GLD16 (no swizzle needed)
#define STAGE(S, B)                                                            \
    {                                                                          \
        _Pragma("unroll") for (int p = 0; p < 4; ++p) {                        \
            int rs = w * 4 + p;                                                \
            GLD16(rnP + (size_t)((rowA0 >> 4) + rs) * 16384 + (S) * 1024 +     \
                      lane * 16,                                               \
                  &As[B][rs * 1024]);                                          \
            GLD16(rnP + (size_t)((colB0 >> 4) + rs) * 16384 + (S) * 1024 +     \
                      lane * 16,                                               \
                  &Bs[B][rs * 1024]);                                          \
        }                                                                      \
    }

    STAGE(0, 0);
    for (int s = 0; s < 16; ++s) {
        __syncthreads();   // seals reads of buf (s-1)&1 and drains staging of s
        int b = s & 1;
        if (s < 15) STAGE(s + 1, b ^ 1);
#pragma unroll
        for (int s2 = 0; s2 < 2; ++s2) {
            i64 af[8], bf[8];
#pragma unroll
            for (int ti = 0; ti < 8; ++ti)
                af[ti] = *(const i64*)&As[b][(wr * 8 + ti) * 1024 + s2 * 512 +
                                             lane * 8];
#pragma unroll
            for (int tj = 0; tj < 8; ++tj)
                bf[tj] = *(const i64*)&Bs[b][(wc * 8 + tj) * 1024 + s2 * 512 +
                                             lane * 8];
#pragma unroll
            for (int ti = 0; ti < 8; ++ti)
#pragma unroll
                for (int tj = 0; tj < 8; ++tj)
                    acc[ti][tj] = __builtin_amdgcn_mfma_f32_16x16x32_fp8_fp8(
                        af[ti], bf[tj], acc[ti][tj], 0, 0, 0);
        }
    }
#undef STAGE

    // epilogue: C layout col=lane&15, row=(lane>>4)*4+reg
    bool isDiag = (bi == bj);
    float colE[8], colP[8];
#pragma unroll
    for (int tj = 0; tj < 8; ++tj) { colE[tj] = 0.f; colP[tj] = 0.f; }
    int lcj[8];
#pragma unroll
    for (int tj = 0; tj < 8; ++tj)
        lcj[tj] = labels[colB0 + wc * 128 + tj * 16 + m_];

#pragma unroll
    for (int ti = 0; ti < 8; ++ti) {
        int rowBase = rowA0 + wr * 128 + ti * 16 + g * 4;
        float rE[4] = {0.f, 0.f, 0.f, 0.f}, rP[4] = {0.f, 0.f, 0.f, 0.f};
        int lr[4];
#pragma unroll
        for (int r = 0; r < 4; ++r) lr[r] = labels[rowBase + r];
#pragma unroll
        for (int tj = 0; tj < 8; ++tj) {
            int gCol = colB0 + wc * 128 + tj * 16 + m_;
            int lc = lcj[tj];
            f32x4 a = acc[ti][tj];
#pragma unroll
            for (int r = 0; r < 4; ++r) {
                int gRow = rowBase + r;
                float z = Z_SCALE * a[r];
                float e = __expf(z);
                bool offd = (gRow != gCol);
                if (!offd) e = 0.f;
                rE[r] += e;
                colE[tj] += e;
                if (offd && (lr[r] == lc)) { rP[r] += z; colP[tj] += z; }
            }
        }
#pragma unroll
        for (int r = 0; r < 4; ++r) {
            float v = rE[r], p = rP[r];
#pragma unroll
            for (int msk = 1; msk < 16; msk <<= 1) {
                v += __shfl_xor(v, msk, 64);
                p += __shfl_xor(p, msk, 64);
            }
            if (m_ == 0) {
                atomicAdd(&denom[rowBase + r], v);
                atomicAdd(&posS[rowBase + r], p);
            }
        }
    }
    if (!isDiag) {
#pragma unroll
        for (int tj = 0; tj < 8; ++tj) {
            float v = colE[tj], p = colP[tj];
            v += __shfl_xor(v, 16, 64); p += __shfl_xor(p, 16, 64);
            v += __shfl_xor(v, 32, 64); p += __shfl_xor(p, 32, 64);
            if (g == 0) {
                int gCol = colB0 + wc * 128 + tj * 16 + m_;
                atomicAdd(&denom[gCol], v);
                atomicAdd(&posS[gCol], p);
            }
        }
    }
}

// ---------------- D3: finalize (8 row-blocks + 8 G-blocks), done-counter ----
__global__ __launch_bounds__(256) void scl_finalize(const float* __restrict__ denom,
                                                    const float* __restrict__ posS,
                                                    const float* __restrict__ sl,
                                                    const int* __restrict__ labels,
                                                    const float* __restrict__ cs_part,
                                                    const int* __restrict__ cc_part,
                                                    const float* __restrict__ Gp,
                                                    const int* __restrict__ pwp,
                                                    double* __restrict__ oacc,
                                                    int* __restrict__ done,
                                                    float* __restrict__ out) {
    int t = threadIdx.x;
    int bits = *pwp;
    float pw = (bits >= -(1 << 22) && bits <= (1 << 22)) ? (float)bits
                                                         : __int_as_float(bits);
    __shared__ double wsum[4];
    double contrib = 0.0;

    if (blockIdx.x < 8) {
        __shared__ __align__(16) float css[32];
        __shared__ int ccs[32];
        if (t < 32) {
            float s = 0.f; int n = 0;
#pragma unroll
            for (int b = 0; b < 32; ++b) {
                s += cs_part[b * 32 + t];
                n += cc_part[b * 32 + t];
            }
            css[t] = s; ccs[t] = n;
        }
        __syncthreads();
        const f32x4* sl4 = (const f32x4*)sl;
        const f32x4* cs4 = (const f32x4*)css;
        double td = 0.0;
#pragma unroll
        for (int h = 0; h < 2; ++h) {
            int i = blockIdx.x * 512 + h * 256 + t;
            float dW = 0.f;
#pragma unroll
            for (int q = 0; q < 8; ++q) {
                f32x4 s = sl4[i * 8 + q];
                f32x4 c = cs4[q];
                dW += s[0] * c[0] + s[1] * c[1] + s[2] * c[2] + s[3] * c[3];
            }
            float Wv = (float)(ccs[labels[i]] - 1) + pw * dW;
            td += (double)(__logf(denom[i]) * Wv - posS[i]);
        }
#pragma unroll
        for (int m = 1; m < 64; m <<= 1) td += __shfl_xor(td, m, 64);
        if ((t & 63) == 0) wsum[t >> 6] = td;
        __syncthreads();
        contrib = wsum[0] + wsum[1] + wsum[2] + wsum[3];
    } else {
        // G-block gb: G[d][c] = sum_{ks<8} Gp[ks][d][c]; accumulate ||G||^2
        int gb = blockIdx.x - 8;
        int c = t & 31, dq = t >> 5;
        float gs = 0.f;
#pragma unroll
        for (int dd = 0; dd < 16; ++dd) {
            int d = gb * 128 + dq * 16 + dd;
            float gv = 0.f;
#pragma unroll
            for (int ks = 0; ks < 8; ++ks)
                gv += Gp[(size_t)ks * 32768 + d * 32 + c];
            gs += gv * gv;
        }
        double gd = (double)gs;
#pragma unroll
        for (int m = 1; m < 64; m <<= 1) gd += __shfl_xor(gd, m, 64);
        if ((t & 63) == 0) wsum[t >> 6] = gd;
        __syncthreads();
        contrib = -(double)(pw * INV_T) * (wsum[0] + wsum[1] + wsum[2] + wsum[3]);
    }

    if (t == 0) {
        atomicAdd(oacc, contrib);
        __threadfence();
        int old = atomicAdd(done, 1);
        if (old == 15) {  // last of 16 blocks
            double tot = atomicAdd(oacc, 0.0);  // coherent read
            out[0] = (float)(tot * (1.0 / 4096.0));
        }
    }
}

// ---------------------------------------------------------------------------
extern "C" void kernel_launch(void* const* d_in, const int* in_sizes, int n_in,
                              void* d_out, int out_size, void* d_ws, size_t ws_size,
                              hipStream_t stream) {
    const float* rep = (const float*)d_in[0];
    const float* sl = (const float*)d_in[1];
    const int* labels = (const int*)d_in[2];
    const int* pwp = (const int*)d_in[3];

    char* ws = (char*)d_ws;
    uint8_t* rnP = (uint8_t*)(ws + OFF_RNF8);
    double* oacc = (double*)(ws + OFF_OACC);
    int* done = (int*)(ws + OFF_DONE);
    float* denom = (float*)(ws + OFF_DENOM);
    float* posS = (float*)(ws + OFF_POSS);
    float* cs_part = (float*)(ws + OFF_CSP);
    int* cc_part = (int*)(ws + OFF_CCP);
    float* Gp = (float*)(ws + OFF_GP);

    scl_stage1<<<297, 256, 0, stream>>>(rep, sl, labels, rnP, cs_part, cc_part,
                                        ws + OFF_OACC);
    scl_main<<<264, 256, 0, stream>>>(rnP, sl, labels, denom, posS, Gp);
    scl_finalize<<<16, 256, 0, stream>>>(denom, posS, sl, labels, cs_part, cc_part,
                                         Gp, pwp, oacc, done, (float*)d_out);
}